// Round 7
// baseline (286.096 us; speedup 1.0000x reference)
//
#include <hip/hip_runtime.h>

constexpr int BATCH = 2048;
constexpr int NHID  = 512;
constexpr int H0    = 256;
constexpr int H1    = 256;
constexpr int S     = 12;   // samples per tile (register-resident)
constexpr int NSLOT = 2;    // tile slots per parent (grid = 256*NSLOT)

// Block (p = bid>>1, slot = bid&1) handles sample tiles slot, slot+2, ... of
// parent p. 256 threads = 4 waves: wave g -> pass = g>>1 (top/bottom),
// class-half h = g&1 (classes [128h,128h+128), 2 classes/lane via float2).
// Each weight element is loaded by exactly ONE wave with all 12 samples
// register-resident -> ~1 MB delivered per block (~280 MB total, vs 768 MB
// in R6 which hit the ~9 TB/s cache-delivery ceiling).
// Softmax: wave-local (m,sum,etgt) per 128-class half; exact flash-merge
// across halves; etgt via shuffle-reduce of (class==tgt ? e : 0) so every
// wave writes deterministically (no conditional-write hazard).
__global__ __launch_bounds__(256) void hs_minbytes(
    const float* __restrict__ x,        // [B, NHID]
    const int*   __restrict__ labels,   // [B]
    const int*   __restrict__ parents,  // [B]
    const float* __restrict__ topW,     // [NHID, H0]
    const float* __restrict__ topb,     // [H0]
    const float* __restrict__ botW,     // [H0, NHID, H1]
    const float* __restrict__ botb,     // [H0, H1]
    float*       __restrict__ out)      // [B]
{
    const int p    = blockIdx.x >> 1;
    const int slot = blockIdx.x & 1;
    const int t    = threadIdx.x;     // 0..255
    const int gb   = t >> 6;          // wave id 0..3 (build + roles)
    const int l    = t & 63;
    const int mypass = gb >> 1;       // 0 = top, 1 = bottom
    const int h      = gb & 1;        // class-half

    __shared__ int   list[BATCH];                   // 8 KB
    __shared__ int   wcnt[4];
    __shared__ __align__(16) float xs[S][NHID];     // 24 KB
    __shared__ float wm[2][2][S], wsum[2][2][S], wet[2][2][S];

    // ---- deterministic ordered list build (R4-verified ballot scan)
    int running = 0;
    for (int c = 0; c < BATCH; c += 256) {
        const bool match = (parents[c + t] == p);
        const unsigned long long mask = __ballot(match);
        if (l == 0) wcnt[gb] = __popcll(mask);
        __syncthreads();
        int off = running;
        for (int w = 0; w < gb; ++w) off += wcnt[w];
        if (match)
            list[off + __popcll(mask & ((1ull << l) - 1ull))] = c + t;
        running += wcnt[0] + wcnt[1] + wcnt[2] + wcnt[3];
        __syncthreads();
    }
    const int n = running;
    if (n <= slot * S) return;   // uniform exit

    // my wave's weight column pointer: 2 classes (128h + 2l, +1)
    const float* Wbase = mypass ? botW + (size_t)p * NHID * H1 : topW;
    const float* Wp    = Wbase + 128 * h + 2 * l;
    const float2 b2    = mypass
        ? *(const float2*)(botb + (size_t)p * H1 + 128 * h + 2 * l)
        : *(const float2*)(topb + 128 * h + 2 * l);
    const int c0 = 128 * h + 2 * l;   // my first class index

    for (int base = slot * S; base < n; base += NSLOT * S) {
        const int rem = min(S, n - base);

        // ---- stage 12 x-rows (2 rows per iteration, 256 thr coalesced)
        for (int pr = 0; pr < S / 2; ++pr) {
            const int row = 2 * pr + (t >> 7);
            const int col = t & 127;
            const int idx = list[base + min(row, rem - 1)];
            ((float4*)xs[row])[col] = ((const float4*)(x + (size_t)idx * NHID))[col];
        }

        // per-sample targets (wave-uniform)
        int tgts[S];
        #pragma unroll
        for (int s = 0; s < S; ++s) {
            const int slotidx = base + min(s, rem - 1);
            tgts[s] = mypass ? labels[list[slotidx]] : p;
        }
        __syncthreads();   // xs ready

        // ---- full-depth GEMV: 12 samples x 2 classes, ring-16 prefetch
        float2 acc[S];
        #pragma unroll
        for (int s = 0; s < S; ++s) acc[s] = make_float2(0.f, 0.f);

        float2 ring[16];
        #pragma unroll
        for (int i = 0; i < 16; ++i)
            ring[i] = *(const float2*)(Wp + (size_t)i * H0);

        #pragma unroll 4
        for (int d4 = 0; d4 < NHID / 4; ++d4) {     // d = 4*d4
            const int rs = (d4 & 3) * 4;            // ring slot (const-folds)
            const float2 w0 = ring[rs + 0], w1 = ring[rs + 1];
            const float2 w2 = ring[rs + 2], w3 = ring[rs + 3];
            const int dn = 4 * d4 + 16;
            if (dn < NHID) {
                #pragma unroll
                for (int i = 0; i < 4; ++i)
                    ring[rs + i] = *(const float2*)(Wp + (size_t)(dn + i) * H0);
            }
            const int d = 4 * d4;
            #pragma unroll
            for (int s = 0; s < S; ++s) {
                const float4 xv = *(const float4*)&xs[s][d];   // LDS b128
                float2 a = acc[s];
                a.x = fmaf(xv.x, w0.x, a.x);  a.y = fmaf(xv.x, w0.y, a.y);
                a.x = fmaf(xv.y, w1.x, a.x);  a.y = fmaf(xv.y, w1.y, a.y);
                a.x = fmaf(xv.z, w2.x, a.x);  a.y = fmaf(xv.z, w2.y, a.y);
                a.x = fmaf(xv.w, w3.x, a.x);  a.y = fmaf(xv.w, w3.y, a.y);
                acc[s] = a;
            }
        }

        // ---- wave-local softmax stats per sample over my 128 classes
        #pragma unroll
        for (int s = 0; s < S; ++s) {
            float2 v = acc[s];
            v.x += b2.x; v.y += b2.y;

            float m = fmaxf(v.x, v.y);
            #pragma unroll
            for (int off = 32; off > 0; off >>= 1)
                m = fmaxf(m, __shfl_xor(m, off, 64));

            const float ex = expf(v.x - m);
            const float ey = expf(v.y - m);
            float sum = ex + ey;
            #pragma unroll
            for (int off = 32; off > 0; off >>= 1)
                sum += __shfl_xor(sum, off, 64);

            // deterministic etgt: reduce (class==tgt ? e : 0) over the wave
            const int tgt = tgts[s];
            float et = (c0 == tgt) ? ex : (c0 + 1 == tgt) ? ey : 0.f;
            #pragma unroll
            for (int off = 32; off > 0; off >>= 1)
                et += __shfl_xor(et, off, 64);

            if (l == 0) {
                wm[mypass][h][s]   = m;
                wsum[mypass][h][s] = sum;
                wet[mypass][h][s]  = et;
            }
        }
        __syncthreads();   // stats complete

        // ---- merge halves (exact flash-softmax) + combine passes
        if (t < rem) {
            float pr[2];
            #pragma unroll
            for (int ps = 0; ps < 2; ++ps) {
                const float m0 = wm[ps][0][t], m1 = wm[ps][1][t];
                const float m  = fmaxf(m0, m1);
                const float a0 = expf(m0 - m), a1 = expf(m1 - m);
                const float sum = wsum[ps][0][t] * a0 + wsum[ps][1][t] * a1;
                const float et  = wet[ps][0][t] * a0 + wet[ps][1][t] * a1;
                pr[ps] = et / sum;
            }
            out[list[base + t]] = pr[0] * pr[1];
        }
        __syncthreads();   // xs/stats safe for next tile
    }
}

extern "C" void kernel_launch(void* const* d_in, const int* in_sizes, int n_in,
                              void* d_out, int out_size, void* d_ws, size_t ws_size,
                              hipStream_t stream) {
    const float* x       = (const float*)d_in[0];
    const int*   labels  = (const int*)  d_in[1];
    const int*   parents = (const int*)  d_in[2];
    const float* topW    = (const float*)d_in[3];
    const float* topb    = (const float*)d_in[4];
    const float* botW    = (const float*)d_in[5];
    const float* botb    = (const float*)d_in[6];
    float*       out     = (float*)d_out;

    hs_minbytes<<<H0 * NSLOT, 256, 0, stream>>>(x, labels, parents,
                                                topW, topb, botW, botb, out);
}

// Round 8
// 244.978 us; speedup vs baseline: 1.1678x; 1.1678x over previous
//
#include <hip/hip_runtime.h>

constexpr int BATCH = 2048;
constexpr int NHID  = 512;
constexpr int H0    = 256;
constexpr int H1    = 256;
constexpr int KCH   = 4;            // depth chunks (split-K)
constexpr int DCH   = NHID / KCH;   // 128 rows per chunk
constexpr int S     = 16;           // samples per register tile
constexpr int LSTRIDE = 2048;       // per-parent list stride (worst case)
constexpr int NBOT  = H0 * KCH;           // 1024 bottom blocks
constexpr int NTOP  = (BATCH / S) * KCH;  // 512 top blocks

// ws layout: list int[256][2048] (2MB) | nval int[256] (4KB pad) |
//            wstop float[2048][4][256] (8.4MB) | wsbot same (8.4MB)

// ---- kernel 1: per-parent sample lists (R4-verified ballot prefix scan)
__global__ __launch_bounds__(256) void k_prep(const int* __restrict__ parents,
                                              int* __restrict__ list,
                                              int* __restrict__ nval) {
    const int p = blockIdx.x, t = threadIdx.x, g = t >> 6, l = t & 63;
    __shared__ int wcnt[4];
    int running = 0;
    for (int c = 0; c < BATCH; c += 256) {
        const bool match = (parents[c + t] == p);
        const unsigned long long mask = __ballot(match);
        if (l == 0) wcnt[g] = __popcll(mask);
        __syncthreads();
        int off = running;
        for (int w = 0; w < g; ++w) off += wcnt[w];
        if (match)
            list[p * LSTRIDE + off + __popcll(mask & ((1ull << l) - 1ull))] = c + t;
        running += wcnt[0] + wcnt[1] + wcnt[2] + wcnt[3];
        __syncthreads();
    }
    if (t == 0) nval[p] = running;
}

// ---- shared GEMV tile: 128 rows (stride 256 floats), 4 classes/lane,
//      S samples; ring-8 float4 prefetch (R6-verified FMA pattern)
__device__ __forceinline__ void gemv_tile(const float* __restrict__ Wp,
                                          const float xs[S][DCH],
                                          float4 acc[S]) {
    float4 ring[8];
    #pragma unroll
    for (int i = 0; i < 8; ++i)
        ring[i] = *(const float4*)(Wp + (size_t)i * 256);

    for (int d = 0; d < DCH; d += 8) {
        #pragma unroll
        for (int h = 0; h < 2; ++h) {
            const int dd = d + 4 * h;
            const float4 w0 = ring[4 * h + 0], w1 = ring[4 * h + 1];
            const float4 w2 = ring[4 * h + 2], w3 = ring[4 * h + 3];
            if (dd + 8 < DCH) {
                #pragma unroll
                for (int i = 0; i < 4; ++i)
                    ring[4 * h + i] =
                        *(const float4*)(Wp + (size_t)(dd + 8 + i) * 256);
            }
            #pragma unroll
            for (int s = 0; s < S; ++s) {
                const float4 xv = *(const float4*)&xs[s][dd];
                float4 a = acc[s];
                a.x = fmaf(xv.x, w0.x, a.x); a.y = fmaf(xv.x, w0.y, a.y);
                a.z = fmaf(xv.x, w0.z, a.z); a.w = fmaf(xv.x, w0.w, a.w);
                a.x = fmaf(xv.y, w1.x, a.x); a.y = fmaf(xv.y, w1.y, a.y);
                a.z = fmaf(xv.y, w1.z, a.z); a.w = fmaf(xv.y, w1.w, a.w);
                a.x = fmaf(xv.z, w2.x, a.x); a.y = fmaf(xv.z, w2.y, a.y);
                a.z = fmaf(xv.z, w2.z, a.z); a.w = fmaf(xv.z, w2.w, a.w);
                a.x = fmaf(xv.w, w3.x, a.x); a.y = fmaf(xv.w, w3.y, a.y);
                a.z = fmaf(xv.w, w3.z, a.z); a.w = fmaf(xv.w, w3.w, a.w);
                acc[s] = a;
            }
        }
    }
}

// ---- kernel 2: split-K partial logits. 1-wave blocks.
//      b < NBOT:  bottom, (p = b>>2, k = b&3), samples from list[p]
//      b >= NBOT: top, (j = (b-NBOT)>>2, k = &3), samples 16j..16j+15
__global__ __launch_bounds__(64) void k_gemv(
    const float* __restrict__ x, const float* __restrict__ topW,
    const float* __restrict__ botW, const int* __restrict__ list,
    const int* __restrict__ nval, float* __restrict__ wstop,
    float* __restrict__ wsbot) {
    const int b = blockIdx.x, l = threadIdx.x;
    __shared__ __align__(16) float xs[S][DCH];   // 8 KB
    __shared__ int sid[S];

    if (b < NBOT) {
        const int p = b >> 2, k = b & 3;
        const int n = nval[p];
        const float* W = botW + ((size_t)p * NHID + (size_t)k * DCH) * H1 + 4 * l;
        for (int tb = 0; tb < n; tb += S) {
            const int rem = min(S, n - tb);
            for (int i = l; i < S; i += 64)
                sid[i] = list[p * LSTRIDE + tb + min(i, rem - 1)];
            __syncthreads();
            for (int i = l; i < S * (DCH / 4); i += 64) {
                const int s = i >> 5, c = i & 31;
                ((float4*)xs[s])[c] =
                    *(const float4*)(x + (size_t)sid[s] * NHID + k * DCH + 4 * c);
            }
            __syncthreads();
            float4 acc[S];
            #pragma unroll
            for (int s = 0; s < S; ++s) acc[s] = make_float4(0.f, 0.f, 0.f, 0.f);
            gemv_tile(W, xs, acc);
            for (int s = 0; s < rem; ++s)
                *(float4*)(wsbot + ((size_t)sid[s] * KCH + k) * H1 + 4 * l) = acc[s];
            __syncthreads();   // xs/sid safe for next tile
        }
    } else {
        const int bb = b - NBOT, j = bb >> 2, k = bb & 3;
        const float* W = topW + (size_t)k * DCH * H0 + 4 * l;
        for (int i = l; i < S * (DCH / 4); i += 64) {
            const int s = i >> 5, c = i & 31;
            ((float4*)xs[s])[c] =
                *(const float4*)(x + (size_t)(S * j + s) * NHID + k * DCH + 4 * c);
        }
        __syncthreads();
        float4 acc[S];
        #pragma unroll
        for (int s = 0; s < S; ++s) acc[s] = make_float4(0.f, 0.f, 0.f, 0.f);
        gemv_tile(W, xs, acc);
        #pragma unroll
        for (int s = 0; s < S; ++s)
            *(float4*)(wstop + ((size_t)(S * j + s) * KCH + k) * H0 + 4 * l) = acc[s];
    }
}

// ---- kernel 3: chunk-sum + bias + wave softmax (R7-verified) + combine
__global__ __launch_bounds__(64) void k_fin(
    const int* __restrict__ labels, const int* __restrict__ parents,
    const float* __restrict__ topb, const float* __restrict__ botb,
    const float* __restrict__ wstop, const float* __restrict__ wsbot,
    float* __restrict__ out) {
    const int s = blockIdx.x, l = threadIdx.x;
    const int par = parents[s];
    float pr[2];
    #pragma unroll
    for (int pass = 0; pass < 2; ++pass) {
        const float* wsrc = pass ? wsbot : wstop;
        float4 v = make_float4(0.f, 0.f, 0.f, 0.f);
        #pragma unroll
        for (int k = 0; k < KCH; ++k) {   // fixed order: deterministic
            const float4 c = *(const float4*)(wsrc + ((size_t)s * KCH + k) * 256 + 4 * l);
            v.x += c.x; v.y += c.y; v.z += c.z; v.w += c.w;
        }
        const float4 bias = pass ? *(const float4*)(botb + (size_t)par * H1 + 4 * l)
                                 : *(const float4*)(topb + 4 * l);
        v.x += bias.x; v.y += bias.y; v.z += bias.z; v.w += bias.w;

        float m = fmaxf(fmaxf(v.x, v.y), fmaxf(v.z, v.w));
        #pragma unroll
        for (int off = 32; off > 0; off >>= 1)
            m = fmaxf(m, __shfl_xor(m, off, 64));

        const float ex = expf(v.x - m), ey = expf(v.y - m);
        const float ez = expf(v.z - m), ew = expf(v.w - m);
        float sum = (ex + ey) + (ez + ew);
        #pragma unroll
        for (int off = 32; off > 0; off >>= 1)
            sum += __shfl_xor(sum, off, 64);

        const int tgt = pass ? labels[s] : par;
        const int c0 = 4 * l;
        float et = (c0 == tgt) ? ex : (c0 + 1 == tgt) ? ey
                 : (c0 + 2 == tgt) ? ez : (c0 + 3 == tgt) ? ew : 0.f;
        #pragma unroll
        for (int off = 32; off > 0; off >>= 1)
            et += __shfl_xor(et, off, 64);

        pr[pass] = et / sum;
    }
    if (l == 0) out[s] = pr[0] * pr[1];
}

extern "C" void kernel_launch(void* const* d_in, const int* in_sizes, int n_in,
                              void* d_out, int out_size, void* d_ws, size_t ws_size,
                              hipStream_t stream) {
    const float* x       = (const float*)d_in[0];
    const int*   labels  = (const int*)  d_in[1];
    const int*   parents = (const int*)  d_in[2];
    const float* topW    = (const float*)d_in[3];
    const float* topb    = (const float*)d_in[4];
    const float* botW    = (const float*)d_in[5];
    const float* botb    = (const float*)d_in[6];
    float*       out     = (float*)d_out;

    int*   list  = (int*)d_ws;
    int*   nval  = (int*)((char*)d_ws + (size_t)H0 * LSTRIDE * sizeof(int));
    float* wstop = (float*)((char*)d_ws + (size_t)H0 * LSTRIDE * sizeof(int) + 4096);
    float* wsbot = wstop + (size_t)BATCH * KCH * H0;

    k_prep<<<H0, 256, 0, stream>>>(parents, list, nval);
    k_gemv<<<NBOT + NTOP, 64, 0, stream>>>(x, topW, botW, list, nval, wstop, wsbot);
    k_fin<<<BATCH, 64, 0, stream>>>(labels, parents, topb, botb, wstop, wsbot, out);
}